// Round 5
// baseline (552.734 us; speedup 1.0000x reference)
//
#include <hip/hip_runtime.h>

// ---------------------------------------------------------------------------
// Qwen3VL text-attention block. IO fp32; internal bf16 MFMA + fp32 accum.
//   K0: fp32 -> bf16 streaming convert of x, [wq;wk;wv], wo
//   K1: fused QKV projection GEMM (bf16, double-buffered global_load_lds with
//       counted vmcnt(8); V written TRANSPOSED)
//   K2: per-head RMSNorm + RoPE, 16-lane group per head, short8 (16B/lane)
//   K3: causal flash attention, 32 q-rows/wave, double-buffered K/V with
//       counted vmcnt(8) prefetch
//   K4: output projection GEMM (same dbuf gemm16 template -> fp32 d_out)
// All MFMA LDS tiles use an XOR granule swizzle:
//   slot(row, kg) = row*G + (kg ^ (row & (G-1)))   (granule = 8 bf16 = 16 B)
// ---------------------------------------------------------------------------

#define S_LEN 2048
#define DIM 4096
#define NH 32
#define NKV 8
#define HD 128
#define SCALE 0.08838834764831845f  // 1/sqrt(128)

typedef __attribute__((ext_vector_type(8))) short short8;
typedef __attribute__((ext_vector_type(4))) float f32x4;

__device__ __forceinline__ float bf2f(unsigned short u) {
  union { unsigned i; float f; } c; c.i = ((unsigned)u) << 16; return c.f;
}
__device__ __forceinline__ unsigned short f2bf(float f) {
  union { float f; unsigned u; } c; c.f = f;
  return (unsigned short)((c.u + 0x7fffu + ((c.u >> 16) & 1u)) >> 16);  // RNE
}
__device__ __forceinline__ void cvt8(const float* __restrict__ g,
                                     unsigned short* __restrict__ d) {
  const float4 a = *(const float4*)g;
  const float4 b = *(const float4*)(g + 4);
  short8 p;
  p[0] = (short)f2bf(a.x); p[1] = (short)f2bf(a.y);
  p[2] = (short)f2bf(a.z); p[3] = (short)f2bf(a.w);
  p[4] = (short)f2bf(b.x); p[5] = (short)f2bf(b.y);
  p[6] = (short)f2bf(b.z); p[7] = (short)f2bf(b.w);
  *(short8*)d = p;
}
__device__ __forceinline__ void storeC(float* p, float v) { *p = v; }
__device__ __forceinline__ void storeC(unsigned short* p, float v) { *p = f2bf(v); }

// ---------------------------------------------------------------------------
// K0: fp32 -> bf16 convert. One thread per 8-elem granule.
// ---------------------------------------------------------------------------
#define G_X   1048576u
#define G_WQ  2097152u
#define G_WK   524288u
#define G_WV   524288u
#define G_QKV (G_WQ + G_WK + G_WV)

__global__ __launch_bounds__(256)
void cvt_all(const float* __restrict__ x,  const float* __restrict__ wq,
             const float* __restrict__ wk, const float* __restrict__ wv,
             const float* __restrict__ wo,
             unsigned short* __restrict__ xb,
             unsigned short* __restrict__ wqkvb,
             unsigned short* __restrict__ wob) {
  const size_t g = (size_t)blockIdx.x * 256 + threadIdx.x;
  if (g < G_X) {
    cvt8(x + g * 8, xb + g * 8);
  } else if (g < G_X + G_QKV) {
    const size_t o = g - G_X;
    const float* s = (o < G_WQ) ? wq + o * 8
                   : (o < G_WQ + G_WK) ? wk + (o - G_WQ) * 8
                                       : wv + (o - G_WQ - G_WK) * 8;
    cvt8(s, wqkvb + o * 8);
  } else {
    const size_t o = g - (G_X + G_QKV);
    cvt8(wo + o * 8, wob + o * 8);
  }
}

// ---------------------------------------------------------------------------
// K1/K4: bf16 GEMM, C = A(MxK) @ B^T. 128x128 tile, BK=64, DOUBLE-BUFFERED
// global_load_lds staging with counted vmcnt(8) (tile kt+1's loads issued
// before computing kt; never drains to 0 in the loop; raw s_barrier, no
// __syncthreads vmcnt(0) drain). 4 waves x (4x4) 16x16x32 MFMA.
// LDS rows (64 k = 8 granules) XOR-swizzled with G=8. LDS 64 KiB -> 2/CU.
// ---------------------------------------------------------------------------
#define STAGE_G(KT, BUF)                                                       \
  {                                                                            \
    const int k0s = (KT) << 6;                                                 \
    unsigned short* la = lsA + (BUF) * 8192;                                   \
    unsigned short* lb = lsB + (BUF) * 8192;                                   \
    _Pragma("unroll")                                                          \
    for (int c = 0; c < 4; ++c) {                                              \
      const int chunk = c * 4 + w;         /* wave-uniform */                  \
      const int row   = chunk * 8 + sr8;                                       \
      const unsigned short* ga = A + (size_t)(m0 + row) * K + k0s + skg * 8;   \
      const unsigned short* gb = B + (size_t)(n0 + row) * K + k0s + skg * 8;   \
      __builtin_amdgcn_global_load_lds(                                        \
          (const __attribute__((address_space(1))) void*)ga,                   \
          (__attribute__((address_space(3))) void*)(la + chunk * 512),         \
          16, 0, 0);                                                           \
      __builtin_amdgcn_global_load_lds(                                        \
          (const __attribute__((address_space(1))) void*)gb,                   \
          (__attribute__((address_space(3))) void*)(lb + chunk * 512),         \
          16, 0, 0);                                                           \
    }                                                                          \
  }

template <int QKV, typename TC>
__global__ __launch_bounds__(256)
void gemm16(const unsigned short* __restrict__ A,
            const unsigned short* __restrict__ B,
            TC* __restrict__ C0,
            unsigned short* __restrict__ Ck,
            unsigned short* __restrict__ Cv, int K) {
  __shared__ unsigned short lsA[2 * 128 * 64];
  __shared__ unsigned short lsB[2 * 128 * 64];

  const int t    = threadIdx.x;
  const int lane = t & 63;
  const int w    = t >> 6;
  const int m0   = blockIdx.y * 128;
  const int n0   = blockIdx.x * 128;

  f32x4 acc[4][4];
#pragma unroll
  for (int a = 0; a < 4; ++a)
#pragma unroll
    for (int b = 0; b < 4; ++b)
#pragma unroll
      for (int e = 0; e < 4; ++e) acc[a][b][e] = 0.f;

  const int l15  = lane & 15;
  const int qd   = lane >> 4;
  const int wr   = w >> 1, wc = w & 1;
  const int sr8  = lane >> 3;                       // staging row in 8-chunk
  const int skg  = (lane & 7) ^ sr8;                // swizzled staging granule
  const int l7   = l15 & 7;

  const int nkb = K >> 6;

  // prologue: stage tile 0 into buffer 0 (latency exposed once)
  STAGE_G(0, 0);

  for (int kb = 0; kb < nkb; ++kb) {
    const int cur = kb & 1;
    const int kn  = (kb + 1 < nkb) ? (kb + 1) : kb;  // clamp; dup harmless
    // issue next tile's 8 loads into the other buffer
    STAGE_G(kn, cur ^ 1);
    // wait only for THIS tile's 8 loads (issued one compute phase ago)
    asm volatile("s_waitcnt vmcnt(8)" ::: "memory");
    __builtin_amdgcn_s_barrier();

    const unsigned short* la = lsA + cur * 8192;
    const unsigned short* lb = lsB + cur * 8192;

    __builtin_amdgcn_s_setprio(1);
#pragma unroll
    for (int half = 0; half < 2; ++half) {
      const int kg = (half * 4 + qd) ^ l7;  // swizzled read granule
      short8 af[4], bf[4];
#pragma unroll
      for (int mi = 0; mi < 4; ++mi)
        af[mi] = *(const short8*)(la + (wr * 64 + mi * 16 + l15) * 64 + kg * 8);
#pragma unroll
      for (int ni = 0; ni < 4; ++ni)
        bf[ni] = *(const short8*)(lb + (wc * 64 + ni * 16 + l15) * 64 + kg * 8);
#pragma unroll
      for (int mi = 0; mi < 4; ++mi)
#pragma unroll
        for (int ni = 0; ni < 4; ++ni)
          acc[mi][ni] = __builtin_amdgcn_mfma_f32_16x16x32_bf16(
              af[mi], bf[ni], acc[mi][ni], 0, 0, 0);
    }
    __builtin_amdgcn_s_setprio(0);
    // all waves done reading `cur` before next iter re-stages into it
    __builtin_amdgcn_s_barrier();
  }

  // epilogue: C/D layout col=lane&15, row=quad*4+reg
#pragma unroll
  for (int mi = 0; mi < 4; ++mi)
#pragma unroll
    for (int i = 0; i < 4; ++i) {
      const int grow = m0 + wr * 64 + mi * 16 + qd * 4 + i;
#pragma unroll
      for (int ni = 0; ni < 4; ++ni) {
        const int gcol = n0 + wc * 64 + ni * 16 + l15;
        if (QKV) {
          if (n0 < 4096)
            storeC((unsigned short*)C0 + (size_t)grow * 4096 + gcol,
                   acc[mi][ni][i]);
          else if (n0 < 5120)
            Ck[(size_t)grow * 1024 + (gcol - 4096)] = f2bf(acc[mi][ni][i]);
          else  // V transposed: vT[d][token]
            Cv[(size_t)(gcol - 5120) * S_LEN + grow] = f2bf(acc[mi][ni][i]);
        } else {
          storeC(C0 + (size_t)grow * 4096 + gcol, acc[mi][ni][i]);
        }
      }
    }
}

// ---------------------------------------------------------------------------
// K2: RMSNorm + RoPE, 16-lane group per head-instance, short8 = 16B/lane
// (Guideline 13). Lane g of a group owns dims g*8..g*8+7; the rotate-half
// partner (d +/- 64) lives in lane g^8 -> one __shfl_xor(.,8) per value.
// RMS reduce = 4 shuffle steps within the 16-lane group. No LDS.
// 256 thr = 16 instances/block; grid 5120 = (2048*32 q + 2048*8 k)/16.
// ---------------------------------------------------------------------------
__global__ __launch_bounds__(256)
void norm_rope(unsigned short* __restrict__ qb, unsigned short* __restrict__ kb,
               const float* __restrict__ cosb, const float* __restrict__ sinb,
               const float* __restrict__ qw, const float* __restrict__ kw) {
  const int t    = threadIdx.x;
  const int g    = t & 15;                        // lane within group
  const int inst = blockIdx.x * 16 + (t >> 4);    // head-instance id

  unsigned short* p; const float* wt; int s; bool isq;
  if (inst < S_LEN * NH) {
    s = inst >> 5;
    p = qb + (size_t)s * (NH * HD) + (inst & 31) * HD;
    wt = qw; isq = true;
  } else {
    const int i2 = inst - S_LEN * NH;
    s = i2 >> 3;
    p = kb + (size_t)s * (NKV * HD) + (i2 & 7) * HD;
    wt = kw; isq = false;
  }
  const int d0 = g * 8;

  const short8 v = *(const short8*)(p + d0);
  float x[8];
  float ss = 0.f;
#pragma unroll
  for (int j = 0; j < 8; ++j) {
    x[j] = bf2f((unsigned short)v[j]);
    ss += x[j] * x[j];
  }
#pragma unroll
  for (int off = 1; off < 16; off <<= 1) ss += __shfl_xor(ss, off);
  const float r = rsqrtf(ss * (1.f / 128.f) + 1e-6f);

  float xn[8];
#pragma unroll
  for (int j = 0; j < 8; ++j) xn[j] = x[j] * r * wt[d0 + j];

  const float sgn = (g < 8) ? -1.f : 1.f;
  const float* cp = cosb + s * HD + d0;
  const float* sp = sinb + s * HD + d0;
  short8 o;
#pragma unroll
  for (int j = 0; j < 8; ++j) {
    const float pr = __shfl_xor(xn[j], 8);   // partner dim d ^ 64
    float ov = xn[j] * cp[j] + sgn * pr * sp[j];
    if (isq) ov *= SCALE;                    // fold softmax scale into q
    o[j] = (short)f2bf(ov);
  }
  *(short8*)(p + d0) = o;
}

// ---------------------------------------------------------------------------
// K3: causal flash attention, MFMA. 4 waves/block, 128 q-rows/block,
// 32 q-rows (2 q-frags) per wave. Double-buffered K/V, counted vmcnt(8)
// prefetch. ks: [key][dgran^key&15]; vt: [d][kgran^d&7]. Fixed-max softmax,
// deferred l-reduction. LDS 73 KB -> 2 blocks/CU.
// ---------------------------------------------------------------------------
#define PSTR 72  // P row stride (shorts)

#define STAGE_KV(KT, BUF)                                                      \
  {                                                                            \
    unsigned short* ksb = ks + (BUF) * 8192;                                   \
    unsigned short* vtb = vt + (BUF) * 8192;                                   \
    _Pragma("unroll")                                                          \
    for (int c = 0; c < 4; ++c) {                                              \
      const int chunk = w * 4 + c;                                             \
      const int key = chunk * 4 + kr16;                                        \
      const int dg  = (lane & 15) ^ (key & 15);                                \
      const unsigned short* gk = kB + (size_t)((KT) * 64 + key) * (NKV * HD) + \
                                 kvh * HD + dg * 8;                            \
      __builtin_amdgcn_global_load_lds(                                        \
          (const __attribute__((address_space(1))) void*)gk,                   \
          (__attribute__((address_space(3))) void*)(ksb + chunk * 512),        \
          16, 0, 0);                                                           \
      const int dv = chunk * 8 + vr8;                                          \
      const unsigned short* gv = vT + (size_t)(kvh * HD + dv) * S_LEN +        \
                                 (KT) * 64 + vkg * 8;                          \
      __builtin_amdgcn_global_load_lds(                                        \
          (const __attribute__((address_space(1))) void*)gv,                   \
          (__attribute__((address_space(3))) void*)(vtb + chunk * 512),        \
          16, 0, 0);                                                           \
    }                                                                          \
  }

__global__ __launch_bounds__(256)
void attn_mfma(const unsigned short* __restrict__ qB,
               const unsigned short* __restrict__ kB,
               const unsigned short* __restrict__ vT,
               unsigned short* __restrict__ oB) {
  __shared__ unsigned short ks[2 * 64 * 128];  // dbuf [key][16 gran, swz]
  __shared__ unsigned short vt[2 * 64 * 128];  // dbuf [d][8 gran, swz]
  __shared__ unsigned short Ps[4 * 16 * PSTR]; // per-wave 16-row P buffer

  const int t    = threadIdx.x;
  const int lane = t & 63;
  const int w    = t >> 6;
  const int h    = blockIdx.y;
  const int qt   = (h & 16) ? (15 - blockIdx.x) : blockIdx.x;  // pair-balanced
  const int q0   = qt * 128;
  const int kvh  = h >> 2;
  const int l15  = lane & 15;
  const int qd   = lane >> 4;
  const int l7   = l15 & 7;

  // staging index helpers
  const int kr16 = lane >> 4;                 // K staging: row within 4-chunk
  const int vr8  = lane >> 3;                 // V staging: row within 8-chunk
  const int vkg  = (lane & 7) ^ (vr8 & 7);    // V staging swizzled granule

  // preload Q A-fragments for 2 q-frags (q pre-scaled by 1/sqrt(d))
  short8 qf[2][4];
#pragma unroll
  for (int f = 0; f < 2; ++f) {
    const unsigned short* qp =
        qB + (size_t)(q0 + w * 32 + f * 16 + l15) * (NH * HD) + h * HD + qd * 8;
#pragma unroll
    for (int s = 0; s < 4; ++s) qf[f][s] = *(const short8*)(qp + s * 32);
  }

  f32x4 O[2][8];
#pragma unroll
  for (int f = 0; f < 2; ++f)
#pragma unroll
    for (int nt = 0; nt < 8; ++nt)
#pragma unroll
      for (int e = 0; e < 4; ++e) O[f][nt][e] = 0.f;
  float l_i[2][4] = {{0.f, 0.f, 0.f, 0.f}, {0.f, 0.f, 0.f, 0.f}};

  unsigned short* Pw = Ps + w * (16 * PSTR);

  const int nkt = 2 * qt + 2;  // tiles of 64 keys covering q0..q0+127

  // prologue: stage tile 0 into buffer 0
  STAGE_KV(0, 0);

  for (int kt = 0; kt < nkt; ++kt) {
    const int cur = kt & 1;
    const int kn  = (kt + 1 < nkt) ? (kt + 1) : kt;  // clamp (dup harmless)
    STAGE_KV(kn, cur ^ 1);
    // wait only for THIS tile's 8 loads (issued one compute-phase ago)
    asm volatile("s_waitcnt vmcnt(8)" ::: "memory");
    __builtin_amdgcn_s_barrier();

    const unsigned short* ksb = ks + cur * 8192;
    const unsigned short* vtb = vt + cur * 8192;

    const int dk = kt - 2 * qt;                 // >=0 on diagonal tiles
    const bool active = (dk <= 0) || (w >= 2);  // wave-uniform
    if (active) {
      // ---- QK^T: reuse each kf across both q-frags
      f32x4 S[2][4];
      __builtin_amdgcn_s_setprio(1);
#pragma unroll
      for (int ct = 0; ct < 4; ++ct) {
#pragma unroll
        for (int e = 0; e < 4; ++e) { S[0][ct][e] = 0.f; S[1][ct][e] = 0.f; }
#pragma unroll
        for (int s = 0; s < 4; ++s) {
          const int kg = (s * 4 + qd) ^ l15;  // G=16 swizzle
          const short8 kf =
              *(const short8*)(ksb + (ct * 16 + l15) * 128 + kg * 8);
          S[0][ct] = __builtin_amdgcn_mfma_f32_16x16x32_bf16(qf[0][s], kf,
                                                             S[0][ct], 0, 0, 0);
          S[1][ct] = __builtin_amdgcn_mfma_f32_16x16x32_bf16(qf[1][s], kf,
                                                             S[1][ct], 0, 0, 0);
        }
      }
      __builtin_amdgcn_s_setprio(0);

      // ---- causal mask (diagonal tiles)
      if (dk >= 0) {
#pragma unroll
        for (int f = 0; f < 2; ++f)
#pragma unroll
          for (int ct = 0; ct < 4; ++ct)
#pragma unroll
            for (int i = 0; i < 4; ++i) {
              const int krel = dk * 64 + ct * 16 + l15;
              const int rrel = w * 32 + f * 16 + qd * 4 + i;
              if (krel > rrel) S[f][ct][i] = -1e30f;
            }
      }

      // ---- P = exp(S) per q-frag: write 16-row P, read A-frags back
      short8 pf[2][2];
#pragma unroll
      for (int f = 0; f < 2; ++f) {
#pragma unroll
        for (int ct = 0; ct < 4; ++ct)
#pragma unroll
          for (int i = 0; i < 4; ++i) {
            const float e = __expf(S[f][ct][i]);
            l_i[f][i] += e;
            Pw[(qd * 4 + i) * PSTR + ct * 16 + l15] = f2bf(e);
          }
        // per-wave DS ops are in-order: these reads complete before the
        // next f's writes to the same rows land
        pf[f][0] = *(const short8*)(Pw + l15 * PSTR + qd * 8);
        pf[f][1] = *(const short8*)(Pw + l15 * PSTR + 32 + qd * 8);
      }

      // ---- PV: O[f] += P[f](16x64) * V(64x128); vf reused across f
      {
        const int kg0 = qd ^ l7;        // half 0, G=8 swizzle (d&7 = l7)
        const int kg1 = (4 + qd) ^ l7;  // half 1
        __builtin_amdgcn_s_setprio(1);
#pragma unroll
        for (int nt = 0; nt < 8; ++nt) {
          const short8 vf0 =
              *(const short8*)(vtb + (nt * 16 + l15) * 64 + kg0 * 8);
          const short8 vf1 =
              *(const short8*)(vtb + (nt * 16 + l15) * 64 + kg1 * 8);
          O[0][nt] = __builtin_amdgcn_mfma_f32_16x16x32_bf16(pf[0][0], vf0,
                                                             O[0][nt], 0, 0, 0);
          O[1][nt] = __builtin_amdgcn_mfma_f32_16x16x32_bf16(pf[1][0], vf0,
                                                             O[1][nt], 0, 0, 0);
          O[0][nt] = __builtin_amdgcn_mfma_f32_16x16x32_bf16(pf[0][1], vf1,
                                                             O[0][nt], 0, 0, 0);
          O[1][nt] = __builtin_amdgcn_mfma_f32_16x16x32_bf16(pf[1][1], vf1,
                                                             O[1][nt], 0, 0, 0);
        }
        __builtin_amdgcn_s_setprio(0);
      }
    }
    // compute on `cur` done before next iter's prefetch overwrites it
    __builtin_amdgcn_s_barrier();
    __builtin_amdgcn_sched_barrier(0);
  }

  // ---- deferred l reduction (16-lane butterfly), then scaled store
  float linv[2][4];
#pragma unroll
  for (int f = 0; f < 2; ++f)
#pragma unroll
    for (int i = 0; i < 4; ++i) {
      float s = l_i[f][i];
#pragma unroll
      for (int off = 1; off < 16; off <<= 1) s += __shfl_xor(s, off);
      linv[f][i] = 1.f / s;
    }
#pragma unroll
  for (int f = 0; f < 2; ++f)
#pragma unroll
    for (int nt = 0; nt < 8; ++nt)
#pragma unroll
      for (int i = 0; i < 4; ++i) {
        const size_t row = (size_t)(q0 + w * 32 + f * 16 + qd * 4 + i);
        oB[row * (NH * HD) + h * HD + nt * 16 + l15] =
            f2bf(O[f][nt][i] * linv[f][i]);
      }
}

// ---------------------------------------------------------------------------
extern "C" void kernel_launch(void* const* d_in, const int* in_sizes, int n_in,
                              void* d_out, int out_size, void* d_ws, size_t ws_size,
                              hipStream_t stream) {
  const float* x    = (const float*)d_in[0];
  const float* cosb = (const float*)d_in[1];
  const float* sinb = (const float*)d_in[2];
  const float* wq   = (const float*)d_in[3];
  const float* wk   = (const float*)d_in[4];
  const float* wv   = (const float*)d_in[5];
  const float* wo   = (const float*)d_in[6];
  const float* qnw  = (const float*)d_in[7];
  const float* knw  = (const float*)d_in[8];

  unsigned short* q     = (unsigned short*)d_ws;            // 2048*4096
  unsigned short* k     = q + (size_t)S_LEN * DIM;          // 2048*1024
  unsigned short* vT    = k + (size_t)S_LEN * NKV * HD;     // 1024*2048
  unsigned short* att   = vT + (size_t)NKV * HD * S_LEN;    // 2048*4096
  unsigned short* xb    = att + (size_t)S_LEN * DIM;        // 2048*4096
  unsigned short* wqkvb = xb + (size_t)S_LEN * DIM;         // 6144*4096
  unsigned short* wob   = wqkvb + (size_t)6144 * DIM;       // 4096*4096

  // K0: convert fp32 inputs to bf16
  cvt_all<<<dim3(24576), dim3(256), 0, stream>>>(x, wq, wk, wv, wo, xb, wqkvb,
                                                 wob);
  // K1: QKV projection, N = 6144 -> 48 col tiles (V stored transposed)
  gemm16<1, unsigned short>
      <<<dim3(48, 16), dim3(256), 0, stream>>>(xb, wqkvb, q, k, vT, DIM);
  // K2: RMSNorm + RoPE, 16-lane group per head, short8 vectorized
  norm_rope<<<dim3((S_LEN * (NH + NKV)) / 16), dim3(256), 0, stream>>>(
      q, k, cosb, sinb, qnw, knw);
  // K3: causal MFMA attention, 128 q-rows/block, dbuf + counted prefetch
  attn_mfma<<<dim3(S_LEN / 128, NH), dim3(256), 0, stream>>>(q, k, vT, att);
  // K4: output projection, N = 4096 -> 32 col tiles
  gemm16<0, float>
      <<<dim3(32, 16), dim3(256), 0, stream>>>(att, wob, (float*)d_out,
                                               nullptr, nullptr, DIM);
}